// Round 1
// baseline (1152.259 us; speedup 1.0000x reference)
//
#include <hip/hip_runtime.h>
#include <math.h>

#define HH 256
#define WW 256
#define AREA 65536
#define CIN 16
#define NS 4          // number of shift scales / projection heads
#define CSUR 128      // sur channels = 8*16
#define NEXT 144      // 16 center + 128 sur
#define NTILE 171     // 18*19/2 lower-triangle 8x8 tiles

__constant__ int c_dy[8] = {-1,-1,-1, 0, 0, 1, 1, 1};
__constant__ int c_dx[8] = {-1, 0, 1,-1, 1,-1, 0, 1};

__device__ __forceinline__ int refl(int v) {
    return v < 0 ? -v : (v > 255 ? 510 - v : v);
}

// ---------------------------------------------------------------------------
// K1: extended Gram  gram[b][s][144][144] (lower triangle), ext = [cen; sur_s]
// grid (64 chunks of 4 rows, s=4, b=4), 192 threads
// ---------------------------------------------------------------------------
__global__ __launch_bounds__(192) void k1_gram(const float* __restrict__ cen,
                                               float* __restrict__ gram) {
    const int chunk = blockIdx.x;
    const int s = blockIdx.y;
    const int b = blockIdx.z;
    const int d = 1 << s;          // shifts 1,2,4,8
    const int t = threadIdx.x;
    const float* cb = cen + (size_t)b * CIN * AREA;

    __shared__ __align__(16) float ext[16 * NEXT];

    // lower-triangle tile (ti >= tj), t = ti*(ti+1)/2 + tj
    int ti = 0, rem = t;
    while (rem > ti) { rem -= (ti + 1); ++ti; }
    const int tj = rem;

    float acc[8][8];
#pragma unroll
    for (int i = 0; i < 8; ++i)
#pragma unroll
        for (int j = 0; j < 8; ++j) acc[i][j] = 0.f;

    for (int rnd = 0; rnd < 64; ++rnd) {
        const int y  = chunk * 4 + (rnd >> 4);
        const int x0 = (rnd & 15) << 4;
        // stage 16 pixels of ext
        for (int v = t; v < 9 * 256; v += 192) {
            const int k   = v >> 8;
            const int cin = (v >> 4) & 15;
            const int px  = v & 15;
            const int x   = x0 + px;
            const float cv = cb[cin * AREA + y * WW + x];
            if (k == 0) {
                ext[px * NEXT + cin] = cv;
            } else {
                const int kk = k - 1;
                const int ry = refl(y + c_dy[kk] * d);
                const int rx = refl(x + c_dx[kk] * d);
                const float sv = cb[cin * AREA + ry * WW + rx];
                ext[px * NEXT + 16 + kk * 16 + cin] = sv - cv;
            }
        }
        __syncthreads();
        if (t < NTILE) {
            for (int p = 0; p < 16; ++p) {
                const float4* fi = reinterpret_cast<const float4*>(&ext[p * NEXT + ti * 8]);
                const float4* fj = reinterpret_cast<const float4*>(&ext[p * NEXT + tj * 8]);
                const float4 a0 = fi[0], a1 = fi[1];
                const float4 b0 = fj[0], b1 = fj[1];
                const float ri[8] = {a0.x,a0.y,a0.z,a0.w,a1.x,a1.y,a1.z,a1.w};
                const float rj[8] = {b0.x,b0.y,b0.z,b0.w,b1.x,b1.y,b1.z,b1.w};
#pragma unroll
                for (int i = 0; i < 8; ++i)
#pragma unroll
                    for (int j = 0; j < 8; ++j)
                        acc[i][j] = fmaf(ri[i], rj[j], acc[i][j]);
            }
        }
        __syncthreads();
    }
    if (t < NTILE) {
        float* gb = gram + (size_t)(b * NS + s) * NEXT * NEXT;
#pragma unroll
        for (int i = 0; i < 8; ++i)
#pragma unroll
            for (int j = 0; j < 8; ++j)
                atomicAdd(&gb[(ti * 8 + i) * NEXT + (tj * 8 + j)], acc[i][j]);
    }
}

// ---------------------------------------------------------------------------
// K2a: A_s[jq][c'] = q_w·G_s ;  normK[ck] = k_row·H_s·k_rowT ; normQ = q·C·qT
// grid (s=4, b=4), 256 threads
// ---------------------------------------------------------------------------
__global__ __launch_bounds__(256) void k2a(const float* __restrict__ q_w,
                                           const float* __restrict__ k_w,
                                           const float* __restrict__ gram,
                                           float* __restrict__ A,
                                           float* __restrict__ normK,
                                           float* __restrict__ normQ) {
    const int s = blockIdx.x, b = blockIdx.y;
    const int t = threadIdx.x;
    __shared__ float kw[CSUR * CSUR];
    const float* kws = k_w + (size_t)s * CSUR * CSUR;
    for (int i = t; i < CSUR * CSUR; i += 256) kw[i] = kws[i];
    __syncthreads();
    const float* g = gram + (size_t)(b * NS + s) * NEXT * NEXT;

    // A
    for (int e = t; e < 64 * CSUR; e += 256) {
        const int jq = e >> 7, cp = e & 127;
        float a = 0.f;
#pragma unroll
        for (int cin = 0; cin < 16; ++cin)
            a = fmaf(q_w[jq * 16 + cin], g[(16 + cp) * NEXT + cin], a);
        A[((size_t)(b * NS + s) * 64 + jq) * CSUR + cp] = a;
    }

    // normK: each ck split across 2 threads (i parity)
    __shared__ float nkpart[CSUR * 2];
    {
        const int ck = t & 127, half = t >> 7;
        const float* kr = &kw[ck * CSUR];
        float accq = 0.f;
        for (int i = half; i < CSUR; i += 2) {
            const float kwi = kr[i];
            float rowacc = 0.f;
            for (int j = 0; j < i; ++j)
                rowacc = fmaf(kr[j], g[(16 + i) * NEXT + 16 + j], rowacc);
            accq += kwi * (2.f * rowacc + kwi * g[(16 + i) * NEXT + 16 + i]);
        }
        nkpart[half * CSUR + ck] = accq;
    }
    __syncthreads();
    if (t < CSUR)
        normK[(size_t)(b * NS + s) * CSUR + t] = nkpart[t] + nkpart[CSUR + t];

    if (s == 0 && t < 64) {
        float nq = 0.f;
#pragma unroll
        for (int c1 = 0; c1 < 16; ++c1) {
            const float q1 = q_w[t * 16 + c1];
            float ra = 0.f;
#pragma unroll
            for (int c2 = 0; c2 < c1; ++c2)
                ra = fmaf(q_w[t * 16 + c2], g[c1 * NEXT + c2], ra);
            nq += q1 * (2.f * ra + q1 * g[c1 * NEXT + c1]);
        }
        normQ[b * 64 + t] = nq;
    }
}

// ---------------------------------------------------------------------------
// K2b: scores -> instance norm -> softmax -> wEff_s[j=(a*16+r)][c']
// grid (a=4, b=4), 256 threads
// ---------------------------------------------------------------------------
__global__ __launch_bounds__(256) void k2b(const float* __restrict__ k_w,
                                           const float* __restrict__ v_w,
                                           const float* __restrict__ A,
                                           const float* __restrict__ normK,
                                           const float* __restrict__ normQ,
                                           float* __restrict__ wEff) {
    const int a = blockIdx.x, b = blockIdx.y;
    const int t = threadIdx.x;
    __shared__ float sc[16 * 128];
    __shared__ float red[256];
    __shared__ float rowred[256];
    __shared__ float rowmax[16], rowsum[16];
    __shared__ float s_mu, s_rs;

    for (int e = t; e < 2048; e += 256) {
        const int r = e >> 7, dd = e & 127;
        const int sk = dd & 3, ck = 32 * a + (dd >> 2);
        const int jq = (r & 3) * 16 + 4 * a + (r >> 2);
        const float* Ar = A + ((size_t)(b * NS + sk) * 64 + jq) * CSUR;
        const float* kr = k_w + ((size_t)sk * CSUR + ck) * CSUR;
        float dot = 0.f;
#pragma unroll 8
        for (int c = 0; c < CSUR; ++c) dot = fmaf(Ar[c], kr[c], dot);
        const float qn = fmaxf(sqrtf(fmaxf(normQ[b * 64 + jq], 0.f)), 1e-12f);
        const float kn = fmaxf(sqrtf(fmaxf(normK[(size_t)(b * NS + sk) * CSUR + ck], 0.f)), 1e-12f);
        sc[e] = dot / (qn * kn * 256.0f);
    }
    __syncthreads();
    // mean
    {
        float p = 0.f;
        for (int e = t; e < 2048; e += 256) p += sc[e];
        red[t] = p; __syncthreads();
        for (int off = 128; off > 0; off >>= 1) {
            if (t < off) red[t] += red[t + off];
            __syncthreads();
        }
        if (t == 0) s_mu = red[0] * (1.f / 2048.f);
        __syncthreads();
    }
    // var
    {
        const float mu = s_mu;
        float p = 0.f;
        for (int e = t; e < 2048; e += 256) { const float z = sc[e] - mu; p += z * z; }
        red[t] = p; __syncthreads();
        for (int off = 128; off > 0; off >>= 1) {
            if (t < off) red[t] += red[t + off];
            __syncthreads();
        }
        if (t == 0) s_rs = rsqrtf(red[0] * (1.f / 2048.f) + 1e-5f);
        __syncthreads();
    }
    const float mu = s_mu, rs = s_rs;
    const int r = t >> 4, l = t & 15;
    // row max
    {
        float m = -1e30f;
#pragma unroll
        for (int j = 0; j < 8; ++j) {
            const float z = (sc[r * 128 + l + j * 16] - mu) * rs;
            m = fmaxf(m, z);
        }
        rowred[t] = m; __syncthreads();
        if (l == 0) {
            float m2 = rowred[r * 16];
            for (int j = 1; j < 16; ++j) m2 = fmaxf(m2, rowred[r * 16 + j]);
            rowmax[r] = m2;
        }
        __syncthreads();
    }
    // row sum of exp
    {
        float p = 0.f;
#pragma unroll
        for (int j = 0; j < 8; ++j) {
            const float z = (sc[r * 128 + l + j * 16] - mu) * rs;
            p += expf(z - rowmax[r]);
        }
        rowred[t] = p; __syncthreads();
        if (l == 0) {
            float p2 = 0.f;
            for (int j = 0; j < 16; ++j) p2 += rowred[r * 16 + j];
            rowsum[r] = p2;
        }
        __syncthreads();
    }
    // attn back into sc
    {
        float vals[8];
#pragma unroll
        for (int j = 0; j < 8; ++j) {
            const float z = (sc[r * 128 + l + j * 16] - mu) * rs;
            vals[j] = expf(z - rowmax[r]) / rowsum[r];
        }
        __syncthreads();
#pragma unroll
        for (int j = 0; j < 8; ++j) sc[r * 128 + l + j * 16] = vals[j];
        __syncthreads();
    }
    // wEff_s[(a*16+r)][c'] = sum_m attn[r][4m+s] * v_w[s][32a+m][c']
    for (int e = t; e < 4 * 16 * 128; e += 256) {
        const int sk = e >> 11, r2 = (e >> 7) & 15, cp = e & 127;
        float w = 0.f;
#pragma unroll
        for (int m = 0; m < 32; ++m)
            w = fmaf(sc[r2 * 128 + 4 * m + sk],
                     v_w[((size_t)sk * CSUR + 32 * a + m) * CSUR + cp], w);
        wEff[((size_t)(b * NS + sk) * 64 + (a * 16 + r2)) * CSUR + cp] = w;
    }
}

// ---------------------------------------------------------------------------
// K2c: wFinal_s[o][c'] = bnscale_o * sum_j out_w[o][j] * wEff_s[j][c']
// grid (s=4, b=4), 256 threads
// ---------------------------------------------------------------------------
__global__ __launch_bounds__(256) void k2c(const float* __restrict__ out_w,
                                           const float* __restrict__ bn_gamma,
                                           const float* __restrict__ bn_var,
                                           const float* __restrict__ wEff,
                                           float* __restrict__ wFinal) {
    const int s = blockIdx.x, b = blockIdx.y;
    const int t = threadIdx.x;
    for (int e = t; e < 16 * 128; e += 256) {
        const int o = e >> 7, cp = e & 127;
        float w = 0.f;
#pragma unroll 8
        for (int j = 0; j < 64; ++j)
            w = fmaf(out_w[o * 64 + j],
                     wEff[((size_t)(b * NS + s) * 64 + j) * CSUR + cp], w);
        const float scale = bn_gamma[o] * rsqrtf(bn_var[o] + 1e-5f);
        wFinal[((size_t)(b * NS + s) * 16 + o) * CSUR + cp] = w * scale;
    }
}

// ---------------------------------------------------------------------------
// K3: out[o,pix] = relu( sum_s wFinal_s[o]·sur_s(pix) + bias_o )
// grid (128 row-pairs, b=4), 256 threads; each thread 2 pixels
// ---------------------------------------------------------------------------
__global__ __launch_bounds__(256) void k3_out(const float* __restrict__ cen,
                                              const float* __restrict__ wFinal,
                                              const float* __restrict__ bn_gamma,
                                              const float* __restrict__ bn_beta,
                                              const float* __restrict__ bn_mean,
                                              const float* __restrict__ bn_var,
                                              float* __restrict__ out) {
    const int by = blockIdx.x;
    const int b  = blockIdx.y;
    const int t  = threadIdx.x;
    __shared__ __align__(16) float wf[NS * CSUR * 16];  // [s][c'][o]
    __shared__ __align__(16) float wc[16 * 16];         // [cin][o]

    for (int e = t; e < NS * CSUR * 16; e += 256) {
        const int s = e >> 11, cp = (e >> 4) & 127, o = e & 15;
        wf[e] = wFinal[((size_t)(b * NS + s) * 16 + o) * CSUR + cp];
    }
    __syncthreads();
    {
        const int cin = t >> 4, o = t & 15;
        float sum = 0.f;
#pragma unroll
        for (int s = 0; s < NS; ++s)
#pragma unroll
            for (int k = 0; k < 8; ++k)
                sum += wf[(s * CSUR + k * 16 + cin) * 16 + o];
        wc[cin * 16 + o] = sum;
    }
    __syncthreads();

    const int x0 = t & 127;
    const int x1 = x0 + 128;
    const int y  = by * 2 + (t >> 7);
    const float* cb = cen + (size_t)b * CIN * AREA;

    float acc0[16], acc1[16];
#pragma unroll
    for (int o = 0; o < 16; ++o) { acc0[o] = 0.f; acc1[o] = 0.f; }

    for (int s = 0; s < NS; ++s) {
        const int d = 1 << s;
        for (int k = 0; k < 8; ++k) {
            const int ry  = refl(y + c_dy[k] * d);
            const int rx0 = refl(x0 + c_dx[k] * d);
            const int rx1 = refl(x1 + c_dx[k] * d);
            const float* crow = cb + ry * WW;
#pragma unroll
            for (int cin = 0; cin < 16; ++cin) {
                const float v0 = crow[cin * AREA + rx0];
                const float v1 = crow[cin * AREA + rx1];
                const float4* w4 = reinterpret_cast<const float4*>(&wf[(s * CSUR + k * 16 + cin) * 16]);
#pragma unroll
                for (int oq = 0; oq < 4; ++oq) {
                    const float4 w = w4[oq];
                    acc0[oq*4+0] = fmaf(w.x, v0, acc0[oq*4+0]); acc1[oq*4+0] = fmaf(w.x, v1, acc1[oq*4+0]);
                    acc0[oq*4+1] = fmaf(w.y, v0, acc0[oq*4+1]); acc1[oq*4+1] = fmaf(w.y, v1, acc1[oq*4+1]);
                    acc0[oq*4+2] = fmaf(w.z, v0, acc0[oq*4+2]); acc1[oq*4+2] = fmaf(w.z, v1, acc1[oq*4+2]);
                    acc0[oq*4+3] = fmaf(w.w, v0, acc0[oq*4+3]); acc1[oq*4+3] = fmaf(w.w, v1, acc1[oq*4+3]);
                }
            }
        }
    }
    // center subtraction
    {
        const float* crow = cb + y * WW;
#pragma unroll
        for (int cin = 0; cin < 16; ++cin) {
            const float v0 = crow[cin * AREA + x0];
            const float v1 = crow[cin * AREA + x1];
            const float4* w4 = reinterpret_cast<const float4*>(&wc[cin * 16]);
#pragma unroll
            for (int oq = 0; oq < 4; ++oq) {
                const float4 w = w4[oq];
                acc0[oq*4+0] = fmaf(-w.x, v0, acc0[oq*4+0]); acc1[oq*4+0] = fmaf(-w.x, v1, acc1[oq*4+0]);
                acc0[oq*4+1] = fmaf(-w.y, v0, acc0[oq*4+1]); acc1[oq*4+1] = fmaf(-w.y, v1, acc1[oq*4+1]);
                acc0[oq*4+2] = fmaf(-w.z, v0, acc0[oq*4+2]); acc1[oq*4+2] = fmaf(-w.z, v1, acc1[oq*4+2]);
                acc0[oq*4+3] = fmaf(-w.w, v0, acc0[oq*4+3]); acc1[oq*4+3] = fmaf(-w.w, v1, acc1[oq*4+3]);
            }
        }
    }
#pragma unroll
    for (int o = 0; o < 16; ++o) {
        const float scale = bn_gamma[o] * rsqrtf(bn_var[o] + 1e-5f);
        const float bias  = bn_beta[o] - bn_mean[o] * scale;
        const float r0 = fmaxf(acc0[o] + bias, 0.f);
        const float r1 = fmaxf(acc1[o] + bias, 0.f);
        out[((size_t)(b * 16 + o) * HH + y) * WW + x0] = r0;
        out[((size_t)(b * 16 + o) * HH + y) * WW + x1] = r1;
    }
}

// ---------------------------------------------------------------------------
extern "C" void kernel_launch(void* const* d_in, const int* in_sizes, int n_in,
                              void* d_out, int out_size, void* d_ws, size_t ws_size,
                              hipStream_t stream) {
    const float* cen      = (const float*)d_in[0];
    const float* q_w      = (const float*)d_in[1];
    const float* k_w      = (const float*)d_in[2];
    const float* v_w      = (const float*)d_in[3];
    const float* out_w    = (const float*)d_in[4];
    const float* bn_gamma = (const float*)d_in[5];
    const float* bn_beta  = (const float*)d_in[6];
    const float* bn_mean  = (const float*)d_in[7];
    const float* bn_var   = (const float*)d_in[8];
    float* out = (float*)d_out;

    char* ws = (char*)d_ws;
    const size_t GRAM_BYTES  = (size_t)4 * NS * NEXT * NEXT * 4;   // 1,327,104
    const size_t A_BYTES     = (size_t)4 * NS * 64 * CSUR * 4;     //   524,288
    const size_t NK_BYTES    = (size_t)4 * NS * CSUR * 4;          //     8,192
    const size_t NQ_BYTES    = (size_t)4 * 64 * 4;                 //     1,024
    const size_t WEFF_BYTES  = (size_t)4 * NS * 64 * CSUR * 4;     //   524,288

    float* gram  = (float*)(ws);
    float* A     = (float*)(ws + GRAM_BYTES);
    float* normK = (float*)(ws + GRAM_BYTES + A_BYTES);
    float* normQ = (float*)(ws + GRAM_BYTES + A_BYTES + NK_BYTES);
    float* wEff  = (float*)(ws + GRAM_BYTES + A_BYTES + NK_BYTES + NQ_BYTES);
    float* wFin  = (float*)(ws + GRAM_BYTES + A_BYTES + NK_BYTES + NQ_BYTES + WEFF_BYTES);

    hipMemsetAsync(gram, 0, GRAM_BYTES, stream);
    k1_gram<<<dim3(64, 4, 4), 192, 0, stream>>>(cen, gram);
    k2a<<<dim3(4, 4), 256, 0, stream>>>(q_w, k_w, gram, A, normK, normQ);
    k2b<<<dim3(4, 4), 256, 0, stream>>>(k_w, v_w, A, normK, normQ, wEff);
    k2c<<<dim3(4, 4), 256, 0, stream>>>(out_w, bn_gamma, bn_var, wEff, wFin);
    k3_out<<<dim3(128, 4), 256, 0, stream>>>(cen, wFin, bn_gamma, bn_beta,
                                             bn_mean, bn_var, out);
}

// Round 2
// 476.229 us; speedup vs baseline: 2.4195x; 2.4195x over previous
//
#include <hip/hip_runtime.h>
#include <math.h>

#define HH 256
#define WW 256
#define AREA 65536
#define CIN 16
#define NS 4          // number of shift scales / projection heads
#define CSUR 128      // sur channels = 8*16
#define NEXT 144      // 16 center + 128 sur
#define NPAIR 45      // 9*10/2 lower-triangle 16x16 tile pairs

typedef __attribute__((ext_vector_type(8))) short bf16x8;
typedef __attribute__((ext_vector_type(4))) float f32x4;

__constant__ int c_dy[8] = {-1,-1,-1, 0, 0, 1, 1, 1};
__constant__ int c_dx[8] = {-1, 0, 1,-1, 1,-1, 0, 1};

__device__ constexpr int CTI[NPAIR] = {
    0, 1,1, 2,2,2, 3,3,3,3, 4,4,4,4,4,
    5,5,5,5,5,5, 6,6,6,6,6,6,6, 7,7,7,7,7,7,7,7,
    8,8,8,8,8,8,8,8,8};
__device__ constexpr int CTJ[NPAIR] = {
    0, 0,1, 0,1,2, 0,1,2,3, 0,1,2,3,4,
    0,1,2,3,4,5, 0,1,2,3,4,5,6, 0,1,2,3,4,5,6,7,
    0,1,2,3,4,5,6,7,8};

__device__ __forceinline__ int refl(int v) {
    return v < 0 ? -v : (v > 255 ? 510 - v : v);
}

__device__ __forceinline__ unsigned f2bf(float x) {
    unsigned u = __builtin_bit_cast(unsigned, x);
    return (u + 0x7FFFu + ((u >> 16) & 1u)) >> 16;   // RNE
}

// write one (hi,lo) bf16x2 pair into the transposed LDS tile
__device__ __forceinline__ void wp(unsigned* __restrict__ hi,
                                   unsigned* __restrict__ lo,
                                   int c, int pxp, float a, float b) {
    const unsigned ha = f2bf(a), hb = f2bf(b);
    hi[c * 16 + pxp] = ha | (hb << 16);
    const float fa = __builtin_bit_cast(float, ha << 16);
    const float fb = __builtin_bit_cast(float, hb << 16);
    const unsigned la = f2bf(a - fa), lb = f2bf(b - fb);
    lo[c * 16 + pxp] = la | (lb << 16);
}

// stage one kstep (32 pixels: row y, cols x0..x0+31) into extT hi/lo
__device__ __forceinline__ void stage_tile(unsigned* __restrict__ hi,
                                           unsigned* __restrict__ lo,
                                           const float* __restrict__ base,
                                           int y, int x0, int cin, int pxp, int d) {
    constexpr int DY[8] = {-1,-1,-1, 0, 0, 1, 1, 1};
    constexpr int DX[8] = {-1, 0, 1,-1, 1,-1, 0, 1};
    const int x = x0 + 2 * pxp;
    const float2 cv = *(const float2*)(base + y * WW + x);
    wp(hi, lo, cin, pxp, cv.x, cv.y);                // center rows 0..15
#pragma unroll
    for (int kk = 0; kk < 8; ++kk) {
        const int ys  = refl(y + DY[kk] * d);
        const int xs0 = refl(x + DX[kk] * d);
        const int xs1 = refl(x + 1 + DX[kk] * d);
        const float* row = base + ys * WW;
        wp(hi, lo, 16 + kk * 16 + cin, pxp, row[xs0] - cv.x, row[xs1] - cv.y);
    }
}

// ---------------------------------------------------------------------------
// K1 (MFMA): gram[b][s][144][144] lower triangle via compensated bf16 MFMA.
// grid (32 row-chunks, s=4, b=4) x 256 threads (4 waves).
// LDS: double-buffered extT[144][32] bf16, hi+lo.
// ---------------------------------------------------------------------------
__global__ __launch_bounds__(256) void k1_gram_mfma(const float* __restrict__ cen,
                                                    float* __restrict__ gram) {
    const int chunk = blockIdx.x;          // 0..31 -> 8 rows each
    const int s = blockIdx.y;
    const int b = blockIdx.z;
    const int d = 1 << s;
    const int t = threadIdx.x;
    const int lane = t & 63, wid = t >> 6;
    const int lr = lane & 15, lg = lane >> 4;
    const int cin = t >> 4, pxp = t & 15;  // staging role: (channel, pixel-pair)
    const int y0 = chunk * 8;
    const float* base = cen + ((size_t)b * CIN + cin) * AREA;

    __shared__ unsigned lds[2][2][NEXT * 16];   // [buf][hi/lo][c*16 + pxpair]

    f32x4 acc[12];
#pragma unroll
    for (int i = 0; i < 12; ++i) acc[i] = (f32x4){0.f, 0.f, 0.f, 0.f};

    stage_tile(lds[0][0], lds[0][1], base, y0, 0, cin, pxp, d);
    __syncthreads();

    for (int st = 0; st < 64; ++st) {
        const int cur = st & 1;
        if (st + 1 < 64) {
            const int y  = y0 + ((st + 1) >> 3);
            const int xx = ((st + 1) & 7) << 5;
            stage_tile(lds[cur ^ 1][0], lds[cur ^ 1][1], base, y, xx, cin, pxp, d);
        }
        // fragment loads: one contiguous 1KB region per 16-channel tile
        const unsigned* mh = lds[cur][0];
        const unsigned* ml = lds[cur][1];
        bf16x8 fh[9], fl[9];
#pragma unroll
        for (int tt = 0; tt < 9; ++tt) {
            const int off = (tt * 16 + lr) * 16 + lg * 4;
            fh[tt] = *(const bf16x8*)(mh + off);
            fl[tt] = *(const bf16x8*)(ml + off);
        }
#pragma unroll
        for (int p = 0; p < NPAIR; ++p) {
            if ((p & 3) == wid) {
                const int i = CTI[p], j = CTJ[p], a = p >> 2;
                acc[a] = __builtin_amdgcn_mfma_f32_16x16x32_bf16(fh[i], fh[j], acc[a], 0, 0, 0);
                acc[a] = __builtin_amdgcn_mfma_f32_16x16x32_bf16(fh[i], fl[j], acc[a], 0, 0, 0);
                acc[a] = __builtin_amdgcn_mfma_f32_16x16x32_bf16(fl[i], fh[j], acc[a], 0, 0, 0);
            }
        }
        __syncthreads();
    }

    float* gb = gram + (size_t)(b * NS + s) * NEXT * NEXT;
#pragma unroll
    for (int p = 0; p < NPAIR; ++p) {
        if ((p & 3) == wid) {
            const int gi0 = CTI[p] * 16 + lg * 4;
            const int gj  = CTJ[p] * 16 + lr;
            const f32x4 a = acc[p >> 2];
#pragma unroll
            for (int r = 0; r < 4; ++r)
                atomicAdd(&gb[(gi0 + r) * NEXT + gj], a[r]);
        }
    }
}

// ---------------------------------------------------------------------------
// K2a: A_s[jq][c'] = q_w·G_s ;  normK[ck] = k_row·H_s·k_rowT ; normQ = q·C·qT
// grid (s=4, b=4), 256 threads
// ---------------------------------------------------------------------------
__global__ __launch_bounds__(256) void k2a(const float* __restrict__ q_w,
                                           const float* __restrict__ k_w,
                                           const float* __restrict__ gram,
                                           float* __restrict__ A,
                                           float* __restrict__ normK,
                                           float* __restrict__ normQ) {
    const int s = blockIdx.x, b = blockIdx.y;
    const int t = threadIdx.x;
    __shared__ float kw[CSUR * CSUR];
    const float* kws = k_w + (size_t)s * CSUR * CSUR;
    for (int i = t; i < CSUR * CSUR; i += 256) kw[i] = kws[i];
    __syncthreads();
    const float* g = gram + (size_t)(b * NS + s) * NEXT * NEXT;

    // A
    for (int e = t; e < 64 * CSUR; e += 256) {
        const int jq = e >> 7, cp = e & 127;
        float a = 0.f;
#pragma unroll
        for (int cin = 0; cin < 16; ++cin)
            a = fmaf(q_w[jq * 16 + cin], g[(16 + cp) * NEXT + cin], a);
        A[((size_t)(b * NS + s) * 64 + jq) * CSUR + cp] = a;
    }

    // normK: each ck split across 2 threads (i parity)
    __shared__ float nkpart[CSUR * 2];
    {
        const int ck = t & 127, half = t >> 7;
        const float* kr = &kw[ck * CSUR];
        float accq = 0.f;
        for (int i = half; i < CSUR; i += 2) {
            const float kwi = kr[i];
            float rowacc = 0.f;
            for (int j = 0; j < i; ++j)
                rowacc = fmaf(kr[j], g[(16 + i) * NEXT + 16 + j], rowacc);
            accq += kwi * (2.f * rowacc + kwi * g[(16 + i) * NEXT + 16 + i]);
        }
        nkpart[half * CSUR + ck] = accq;
    }
    __syncthreads();
    if (t < CSUR)
        normK[(size_t)(b * NS + s) * CSUR + t] = nkpart[t] + nkpart[CSUR + t];

    if (s == 0 && t < 64) {
        float nq = 0.f;
#pragma unroll
        for (int c1 = 0; c1 < 16; ++c1) {
            const float q1 = q_w[t * 16 + c1];
            float ra = 0.f;
#pragma unroll
            for (int c2 = 0; c2 < c1; ++c2)
                ra = fmaf(q_w[t * 16 + c2], g[c1 * NEXT + c2], ra);
            nq += q1 * (2.f * ra + q1 * g[c1 * NEXT + c1]);
        }
        normQ[b * 64 + t] = nq;
    }
}

// ---------------------------------------------------------------------------
// K2b: scores -> instance norm -> softmax -> wEff_s[j=(a*16+r)][c']
// grid (a=4, b=4), 256 threads
// ---------------------------------------------------------------------------
__global__ __launch_bounds__(256) void k2b(const float* __restrict__ k_w,
                                           const float* __restrict__ v_w,
                                           const float* __restrict__ A,
                                           const float* __restrict__ normK,
                                           const float* __restrict__ normQ,
                                           float* __restrict__ wEff) {
    const int a = blockIdx.x, b = blockIdx.y;
    const int t = threadIdx.x;
    __shared__ float sc[16 * 128];
    __shared__ float red[256];
    __shared__ float rowred[256];
    __shared__ float rowmax[16], rowsum[16];
    __shared__ float s_mu, s_rs;

    for (int e = t; e < 2048; e += 256) {
        const int r = e >> 7, dd = e & 127;
        const int sk = dd & 3, ck = 32 * a + (dd >> 2);
        const int jq = (r & 3) * 16 + 4 * a + (r >> 2);
        const float* Ar = A + ((size_t)(b * NS + sk) * 64 + jq) * CSUR;
        const float* kr = k_w + ((size_t)sk * CSUR + ck) * CSUR;
        float dot = 0.f;
#pragma unroll 8
        for (int c = 0; c < CSUR; ++c) dot = fmaf(Ar[c], kr[c], dot);
        const float qn = fmaxf(sqrtf(fmaxf(normQ[b * 64 + jq], 0.f)), 1e-12f);
        const float kn = fmaxf(sqrtf(fmaxf(normK[(size_t)(b * NS + sk) * CSUR + ck], 0.f)), 1e-12f);
        sc[e] = dot / (qn * kn * 256.0f);
    }
    __syncthreads();
    // mean
    {
        float p = 0.f;
        for (int e = t; e < 2048; e += 256) p += sc[e];
        red[t] = p; __syncthreads();
        for (int off = 128; off > 0; off >>= 1) {
            if (t < off) red[t] += red[t + off];
            __syncthreads();
        }
        if (t == 0) s_mu = red[0] * (1.f / 2048.f);
        __syncthreads();
    }
    // var
    {
        const float mu = s_mu;
        float p = 0.f;
        for (int e = t; e < 2048; e += 256) { const float z = sc[e] - mu; p += z * z; }
        red[t] = p; __syncthreads();
        for (int off = 128; off > 0; off >>= 1) {
            if (t < off) red[t] += red[t + off];
            __syncthreads();
        }
        if (t == 0) s_rs = rsqrtf(red[0] * (1.f / 2048.f) + 1e-5f);
        __syncthreads();
    }
    const float mu = s_mu, rs = s_rs;
    const int r = t >> 4, l = t & 15;
    // row max
    {
        float m = -1e30f;
#pragma unroll
        for (int j = 0; j < 8; ++j) {
            const float z = (sc[r * 128 + l + j * 16] - mu) * rs;
            m = fmaxf(m, z);
        }
        rowred[t] = m; __syncthreads();
        if (l == 0) {
            float m2 = rowred[r * 16];
            for (int j = 1; j < 16; ++j) m2 = fmaxf(m2, rowred[r * 16 + j]);
            rowmax[r] = m2;
        }
        __syncthreads();
    }
    // row sum of exp
    {
        float p = 0.f;
#pragma unroll
        for (int j = 0; j < 8; ++j) {
            const float z = (sc[r * 128 + l + j * 16] - mu) * rs;
            p += expf(z - rowmax[r]);
        }
        rowred[t] = p; __syncthreads();
        if (l == 0) {
            float p2 = 0.f;
            for (int j = 0; j < 16; ++j) p2 += rowred[r * 16 + j];
            rowsum[r] = p2;
        }
        __syncthreads();
    }
    // attn back into sc
    {
        float vals[8];
#pragma unroll
        for (int j = 0; j < 8; ++j) {
            const float z = (sc[r * 128 + l + j * 16] - mu) * rs;
            vals[j] = expf(z - rowmax[r]) / rowsum[r];
        }
        __syncthreads();
#pragma unroll
        for (int j = 0; j < 8; ++j) sc[r * 128 + l + j * 16] = vals[j];
        __syncthreads();
    }
    // wEff_s[(a*16+r)][c'] = sum_m attn[r][4m+s] * v_w[s][32a+m][c']
    for (int e = t; e < 4 * 16 * 128; e += 256) {
        const int sk = e >> 11, r2 = (e >> 7) & 15, cp = e & 127;
        float w = 0.f;
#pragma unroll
        for (int m = 0; m < 32; ++m)
            w = fmaf(sc[r2 * 128 + 4 * m + sk],
                     v_w[((size_t)sk * CSUR + 32 * a + m) * CSUR + cp], w);
        wEff[((size_t)(b * NS + sk) * 64 + (a * 16 + r2)) * CSUR + cp] = w;
    }
}

// ---------------------------------------------------------------------------
// K2c: wFinal_s[o][c'] = bnscale_o * sum_j out_w[o][j] * wEff_s[j][c']
// grid (s=4, b=4), 256 threads
// ---------------------------------------------------------------------------
__global__ __launch_bounds__(256) void k2c(const float* __restrict__ out_w,
                                           const float* __restrict__ bn_gamma,
                                           const float* __restrict__ bn_var,
                                           const float* __restrict__ wEff,
                                           float* __restrict__ wFinal) {
    const int s = blockIdx.x, b = blockIdx.y;
    const int t = threadIdx.x;
    for (int e = t; e < 16 * 128; e += 256) {
        const int o = e >> 7, cp = e & 127;
        float w = 0.f;
#pragma unroll 8
        for (int j = 0; j < 64; ++j)
            w = fmaf(out_w[o * 64 + j],
                     wEff[((size_t)(b * NS + s) * 64 + j) * CSUR + cp], w);
        const float scale = bn_gamma[o] * rsqrtf(bn_var[o] + 1e-5f);
        wFinal[((size_t)(b * NS + s) * 16 + o) * CSUR + cp] = w * scale;
    }
}

// ---------------------------------------------------------------------------
// K3: out[o,pix] = relu( sum_s wFinal_s[o]·sur_s(pix) + bias_o )
// grid (128 row-pairs, b=4), 256 threads; each thread 2 pixels
// ---------------------------------------------------------------------------
__global__ __launch_bounds__(256) void k3_out(const float* __restrict__ cen,
                                              const float* __restrict__ wFinal,
                                              const float* __restrict__ bn_gamma,
                                              const float* __restrict__ bn_beta,
                                              const float* __restrict__ bn_mean,
                                              const float* __restrict__ bn_var,
                                              float* __restrict__ out) {
    const int by = blockIdx.x;
    const int b  = blockIdx.y;
    const int t  = threadIdx.x;
    __shared__ __align__(16) float wf[NS * CSUR * 16];  // [s][c'][o]
    __shared__ __align__(16) float wc[16 * 16];         // [cin][o]

    for (int e = t; e < NS * CSUR * 16; e += 256) {
        const int s = e >> 11, cp = (e >> 4) & 127, o = e & 15;
        wf[e] = wFinal[((size_t)(b * NS + s) * 16 + o) * CSUR + cp];
    }
    __syncthreads();
    {
        const int cin = t >> 4, o = t & 15;
        float sum = 0.f;
#pragma unroll
        for (int s = 0; s < NS; ++s)
#pragma unroll
            for (int k = 0; k < 8; ++k)
                sum += wf[(s * CSUR + k * 16 + cin) * 16 + o];
        wc[cin * 16 + o] = sum;
    }
    __syncthreads();

    const int x0 = t & 127;
    const int x1 = x0 + 128;
    const int y  = by * 2 + (t >> 7);
    const float* cb = cen + (size_t)b * CIN * AREA;

    float acc0[16], acc1[16];
#pragma unroll
    for (int o = 0; o < 16; ++o) { acc0[o] = 0.f; acc1[o] = 0.f; }

    for (int s = 0; s < NS; ++s) {
        const int d = 1 << s;
        for (int k = 0; k < 8; ++k) {
            const int ry  = refl(y + c_dy[k] * d);
            const int rx0 = refl(x0 + c_dx[k] * d);
            const int rx1 = refl(x1 + c_dx[k] * d);
            const float* crow = cb + ry * WW;
#pragma unroll
            for (int cin = 0; cin < 16; ++cin) {
                const float v0 = crow[cin * AREA + rx0];
                const float v1 = crow[cin * AREA + rx1];
                const float4* w4 = reinterpret_cast<const float4*>(&wf[(s * CSUR + k * 16 + cin) * 16]);
#pragma unroll
                for (int oq = 0; oq < 4; ++oq) {
                    const float4 w = w4[oq];
                    acc0[oq*4+0] = fmaf(w.x, v0, acc0[oq*4+0]); acc1[oq*4+0] = fmaf(w.x, v1, acc1[oq*4+0]);
                    acc0[oq*4+1] = fmaf(w.y, v0, acc0[oq*4+1]); acc1[oq*4+1] = fmaf(w.y, v1, acc1[oq*4+1]);
                    acc0[oq*4+2] = fmaf(w.z, v0, acc0[oq*4+2]); acc1[oq*4+2] = fmaf(w.z, v1, acc1[oq*4+2]);
                    acc0[oq*4+3] = fmaf(w.w, v0, acc0[oq*4+3]); acc1[oq*4+3] = fmaf(w.w, v1, acc1[oq*4+3]);
                }
            }
        }
    }
    // center subtraction
    {
        const float* crow = cb + y * WW;
#pragma unroll
        for (int cin = 0; cin < 16; ++cin) {
            const float v0 = crow[cin * AREA + x0];
            const float v1 = crow[cin * AREA + x1];
            const float4* w4 = reinterpret_cast<const float4*>(&wc[cin * 16]);
#pragma unroll
            for (int oq = 0; oq < 4; ++oq) {
                const float4 w = w4[oq];
                acc0[oq*4+0] = fmaf(-w.x, v0, acc0[oq*4+0]); acc1[oq*4+0] = fmaf(-w.x, v1, acc1[oq*4+0]);
                acc0[oq*4+1] = fmaf(-w.y, v0, acc0[oq*4+1]); acc1[oq*4+1] = fmaf(-w.y, v1, acc1[oq*4+1]);
                acc0[oq*4+2] = fmaf(-w.z, v0, acc0[oq*4+2]); acc1[oq*4+2] = fmaf(-w.z, v1, acc1[oq*4+2]);
                acc0[oq*4+3] = fmaf(-w.w, v0, acc0[oq*4+3]); acc1[oq*4+3] = fmaf(-w.w, v1, acc1[oq*4+3]);
            }
        }
    }
#pragma unroll
    for (int o = 0; o < 16; ++o) {
        const float scale = bn_gamma[o] * rsqrtf(bn_var[o] + 1e-5f);
        const float bias  = bn_beta[o] - bn_mean[o] * scale;
        const float r0 = fmaxf(acc0[o] + bias, 0.f);
        const float r1 = fmaxf(acc1[o] + bias, 0.f);
        out[((size_t)(b * 16 + o) * HH + y) * WW + x0] = r0;
        out[((size_t)(b * 16 + o) * HH + y) * WW + x1] = r1;
    }
}

// ---------------------------------------------------------------------------
extern "C" void kernel_launch(void* const* d_in, const int* in_sizes, int n_in,
                              void* d_out, int out_size, void* d_ws, size_t ws_size,
                              hipStream_t stream) {
    const float* cen      = (const float*)d_in[0];
    const float* q_w      = (const float*)d_in[1];
    const float* k_w      = (const float*)d_in[2];
    const float* v_w      = (const float*)d_in[3];
    const float* out_w    = (const float*)d_in[4];
    const float* bn_gamma = (const float*)d_in[5];
    const float* bn_beta  = (const float*)d_in[6];
    const float* bn_mean  = (const float*)d_in[7];
    const float* bn_var   = (const float*)d_in[8];
    float* out = (float*)d_out;

    char* ws = (char*)d_ws;
    const size_t GRAM_BYTES  = (size_t)4 * NS * NEXT * NEXT * 4;   // 1,327,104
    const size_t A_BYTES     = (size_t)4 * NS * 64 * CSUR * 4;     //   524,288
    const size_t NK_BYTES    = (size_t)4 * NS * CSUR * 4;          //     8,192
    const size_t NQ_BYTES    = (size_t)4 * 64 * 4;                 //     1,024
    const size_t WEFF_BYTES  = (size_t)4 * NS * 64 * CSUR * 4;     //   524,288

    float* gram  = (float*)(ws);
    float* A     = (float*)(ws + GRAM_BYTES);
    float* normK = (float*)(ws + GRAM_BYTES + A_BYTES);
    float* normQ = (float*)(ws + GRAM_BYTES + A_BYTES + NK_BYTES);
    float* wEff  = (float*)(ws + GRAM_BYTES + A_BYTES + NK_BYTES + NQ_BYTES);
    float* wFin  = (float*)(ws + GRAM_BYTES + A_BYTES + NK_BYTES + NQ_BYTES + WEFF_BYTES);

    hipMemsetAsync(gram, 0, GRAM_BYTES, stream);
    k1_gram_mfma<<<dim3(32, 4, 4), 256, 0, stream>>>(cen, gram);
    k2a<<<dim3(4, 4), 256, 0, stream>>>(q_w, k_w, gram, A, normK, normQ);
    k2b<<<dim3(4, 4), 256, 0, stream>>>(k_w, v_w, A, normK, normQ, wEff);
    k2c<<<dim3(4, 4), 256, 0, stream>>>(out_w, bn_gamma, bn_var, wEff, wFin);
    k3_out<<<dim3(128, 4), 256, 0, stream>>>(cen, wFin, bn_gamma, bn_beta,
                                             bn_mean, bn_var, out);
}

// Round 5
// 352.071 us; speedup vs baseline: 3.2728x; 1.3527x over previous
//
#include <hip/hip_runtime.h>
#include <math.h>

#define HH 256
#define WW 256
#define AREA 65536
#define CIN 16
#define NS 4
#define CSUR 128
#define NEXT 144
#define NPAIR 45      // 9*10/2 lower-triangle 16x16 tile pairs

typedef __attribute__((ext_vector_type(8))) short bf16x8;
typedef __attribute__((ext_vector_type(4))) float f32x4;

__constant__ int c_dy[8] = {-1,-1,-1, 0, 0, 1, 1, 1};
__constant__ int c_dx[8] = {-1, 0, 1,-1, 1,-1, 0, 1};

__device__ constexpr int CTI[NPAIR] = {
    0, 1,1, 2,2,2, 3,3,3,3, 4,4,4,4,4,
    5,5,5,5,5,5, 6,6,6,6,6,6,6, 7,7,7,7,7,7,7,7,
    8,8,8,8,8,8,8,8,8};
__device__ constexpr int CTJ[NPAIR] = {
    0, 0,1, 0,1,2, 0,1,2,3, 0,1,2,3,4,
    0,1,2,3,4,5, 0,1,2,3,4,5,6, 0,1,2,3,4,5,6,7,
    0,1,2,3,4,5,6,7,8};

__device__ __forceinline__ int refl(int v) {
    return v < 0 ? -v : (v > 255 ? 510 - v : v);
}

__device__ __forceinline__ unsigned f2bf(float x) {
    unsigned u = __builtin_bit_cast(unsigned, x);
    return (u + 0x7FFFu + ((u >> 16) & 1u)) >> 16;   // RNE
}

// write one (hi,lo) bf16x2 pair into the transposed LDS tile
__device__ __forceinline__ void wp(unsigned* __restrict__ hi,
                                   unsigned* __restrict__ lo,
                                   int c, int pxp, float a, float b) {
    const unsigned ha = f2bf(a), hb = f2bf(b);
    hi[c * 16 + pxp] = ha | (hb << 16);
    const float fa = __builtin_bit_cast(float, ha << 16);
    const float fb = __builtin_bit_cast(float, hb << 16);
    const unsigned la = f2bf(a - fa), lb = f2bf(b - fb);
    lo[c * 16 + pxp] = la | (lb << 16);
}

// stage one kstep (32 pixels: row y, cols x0..x0+31) into extT hi/lo
__device__ __forceinline__ void stage_tile(unsigned* __restrict__ hi,
                                           unsigned* __restrict__ lo,
                                           const float* __restrict__ base,
                                           int y, int x0, int cin, int pxp, int d) {
    constexpr int DY[8] = {-1,-1,-1, 0, 0, 1, 1, 1};
    constexpr int DX[8] = {-1, 0, 1,-1, 1,-1, 0, 1};
    const int x = x0 + 2 * pxp;
    const float2 cv = *(const float2*)(base + y * WW + x);
    wp(hi, lo, cin, pxp, cv.x, cv.y);                // center rows 0..15
#pragma unroll
    for (int kk = 0; kk < 8; ++kk) {
        const int ys  = refl(y + DY[kk] * d);
        const int xs0 = refl(x + DX[kk] * d);
        const int xs1 = refl(x + 1 + DX[kk] * d);
        const float* row = base + ys * WW;
        wp(hi, lo, 16 + kk * 16 + cin, pxp, row[xs0] - cv.x, row[xs1] - cv.y);
    }
}

// ---------------------------------------------------------------------------
// K1 (MFMA): diff Gram gram[b][s][144][144] (lower-tri tiles) via compensated
// bf16 MFMA (round-2 proven path). Writes 4 partial buffers (chunk&3).
// grid (32 chunks x 8 rows, s=4, b=4), 256 threads (4 waves).
// ---------------------------------------------------------------------------
__global__ __launch_bounds__(256) void k1_gram_mfma(const float* __restrict__ cen,
                                                    float* __restrict__ Tpart) {
    const int chunk = blockIdx.x;          // 0..31 -> 8 rows each
    const int s = blockIdx.y;
    const int b = blockIdx.z;
    const int d = 1 << s;
    const int t = threadIdx.x;
    const int lane = t & 63, wid = t >> 6;
    const int lr = lane & 15, lg = lane >> 4;
    const int cin = t >> 4, pxp = t & 15;  // staging role: (channel, pixel-pair)
    const int y0 = chunk * 8;
    const float* base = cen + ((size_t)b * CIN + cin) * AREA;

    __shared__ unsigned lds[2][2][NEXT * 16];   // [buf][hi/lo][c*16 + pxpair]

    f32x4 acc[12];
#pragma unroll
    for (int i = 0; i < 12; ++i) acc[i] = (f32x4){0.f, 0.f, 0.f, 0.f};

    stage_tile(lds[0][0], lds[0][1], base, y0, 0, cin, pxp, d);
    __syncthreads();

    for (int st = 0; st < 64; ++st) {
        const int cur = st & 1;
        if (st + 1 < 64) {
            const int y  = y0 + ((st + 1) >> 3);
            const int xx = ((st + 1) & 7) << 5;
            stage_tile(lds[cur ^ 1][0], lds[cur ^ 1][1], base, y, xx, cin, pxp, d);
        }
        // fragment loads: one contiguous 1KB region per 16-channel tile
        const unsigned* mh = lds[cur][0];
        const unsigned* ml = lds[cur][1];
        bf16x8 fh[9], fl[9];
#pragma unroll
        for (int tt = 0; tt < 9; ++tt) {
            const int off = (tt * 16 + lr) * 16 + lg * 4;
            fh[tt] = *(const bf16x8*)(mh + off);
            fl[tt] = *(const bf16x8*)(ml + off);
        }
#pragma unroll
        for (int p = 0; p < NPAIR; ++p) {
            if ((p & 3) == wid) {
                const int i = CTI[p], j = CTJ[p], a = p >> 2;
                acc[a] = __builtin_amdgcn_mfma_f32_16x16x32_bf16(fh[i], fh[j], acc[a], 0, 0, 0);
                acc[a] = __builtin_amdgcn_mfma_f32_16x16x32_bf16(fh[i], fl[j], acc[a], 0, 0, 0);
                acc[a] = __builtin_amdgcn_mfma_f32_16x16x32_bf16(fl[i], fh[j], acc[a], 0, 0, 0);
            }
        }
        __syncthreads();
    }

    float* tb = Tpart + (size_t)((chunk & 3) * 16 + b * 4 + s) * (144 * 144);
#pragma unroll
    for (int p = 0; p < NPAIR; ++p) {
        if ((p & 3) == wid) {
            const int gi0 = CTI[p] * 16 + lg * 4;
            const int gj  = CTJ[p] * 16 + lr;
            const f32x4 a = acc[p >> 2];
#pragma unroll
            for (int r = 0; r < 4; ++r)
                atomicAdd(&tb[(gi0 + r) * 144 + gj], a[r]);
        }
    }
}

// ---------------------------------------------------------------------------
// K1b: sum 4 partials + mirror lower triangle -> full symmetric Gfull.
// grid (s=4, b=4), 256 threads.
// ---------------------------------------------------------------------------
__global__ __launch_bounds__(256) void k1b(const float* __restrict__ Tpart,
                                           float* __restrict__ Gfull) {
    const int s = blockIdx.x, b = blockIdx.y, bs = b * 4 + s;
    const int t = threadIdx.x;
    __shared__ float Ts[144][145];
    const float* t0 = Tpart + (size_t)(0 * 16 + bs) * 20736;
    const float* t1 = Tpart + (size_t)(1 * 16 + bs) * 20736;
    const float* t2 = Tpart + (size_t)(2 * 16 + bs) * 20736;
    const float* t3 = Tpart + (size_t)(3 * 16 + bs) * 20736;
    for (int e = t; e < 20736; e += 256) {
        const int i = e / 144, j = e - i * 144;
        if (i >= j) {
            const float v = t0[e] + t1[e] + t2[e] + t3[e];
            Ts[i][j] = v;
            Ts[j][i] = v;
        }
    }
    __syncthreads();
    float* go = Gfull + (size_t)bs * 20736;
    for (int e = t; e < 20736; e += 256) {
        const int i = e / 144, j = e - i * 144;
        go[e] = Ts[i][j];
    }
}

// ---------------------------------------------------------------------------
// K2a: A = q_w·G ; normK[ck] = k_row·H·k_rowT ; normQ. grid (s,b,z=4), 256thr.
// ---------------------------------------------------------------------------
__global__ __launch_bounds__(256) void k2a(const float* __restrict__ q_w,
                                           const float* __restrict__ k_w,
                                           const float* __restrict__ Gfull,
                                           float* __restrict__ A,
                                           float* __restrict__ normK,
                                           float* __restrict__ normQ) {
    const int s = blockIdx.x, b = blockIdx.y, z = blockIdx.z;
    const int t = threadIdx.x;
    const float* g = Gfull + (size_t)(b * 4 + s) * 20736;
    __shared__ float kwS[32][132];
    __shared__ float red[8][32];
    for (int idx = t; idx < 4096; idx += 256) {
        const int ckl = idx >> 7, j = idx & 127;
        kwS[ckl][j] = k_w[(size_t)(s * 128 + z * 32 + ckl) * 128 + j];
    }
    __syncthreads();
    // A (16 jq rows per z)
    {
        const int jq = z * 16 + (t >> 4);
        const int cp0 = (t & 15) * 8;
        const float* qrow = q_w + jq * 16;
#pragma unroll
        for (int u = 0; u < 8; ++u) {
            const int cp = cp0 + u;
            const float* grow = g + (16 + cp) * 144;
            float a = 0.f;
#pragma unroll
            for (int cin = 0; cin < 16; ++cin) a = fmaf(qrow[cin], grow[cin], a);
            A[((size_t)(b * 4 + s) * 64 + jq) * 128 + cp] = a;
        }
    }
    // normK (32 ck rows per z, i-range split 8 ways)
    {
        const int ckl = t & 31, gq = t >> 5;
        const float4* krow = (const float4*)(&kwS[ckl][0]);
        float accq = 0.f;
        for (int i = gq * 16; i < gq * 16 + 16; ++i) {
            const float4* hrow = (const float4*)(g + (16 + i) * 144 + 16);
            float4 pv = {0.f, 0.f, 0.f, 0.f};
#pragma unroll 8
            for (int jj = 0; jj < 32; ++jj) {
                const float4 h = hrow[jj], k4 = krow[jj];
                pv.x = fmaf(h.x, k4.x, pv.x);
                pv.y = fmaf(h.y, k4.y, pv.y);
                pv.z = fmaf(h.z, k4.z, pv.z);
                pv.w = fmaf(h.w, k4.w, pv.w);
            }
            accq = fmaf(kwS[ckl][i], pv.x + pv.y + pv.z + pv.w, accq);
        }
        red[gq][ckl] = accq;
    }
    __syncthreads();
    if (t < 32) {
        float sum = 0.f;
#pragma unroll
        for (int q = 0; q < 8; ++q) sum += red[q][t];
        normK[(size_t)(b * 4 + s) * 128 + z * 32 + t] = sum;
    }
    if (s == 0 && z == 0 && t < 64) {
        float nq = 0.f;
#pragma unroll
        for (int c1 = 0; c1 < 16; ++c1) {
            float ra = 0.f;
#pragma unroll
            for (int c2 = 0; c2 < 16; ++c2)
                ra = fmaf(q_w[t * 16 + c2], g[c1 * 144 + c2], ra);
            nq = fmaf(q_w[t * 16 + c1], ra, nq);
        }
        normQ[b * 64 + t] = nq;
    }
}

// ---------------------------------------------------------------------------
// K2b: scores -> instance norm -> softmax -> wEff. grid (a=4, b=4), 256 thr.
// ---------------------------------------------------------------------------
__global__ __launch_bounds__(256) void k2b(const float* __restrict__ k_w,
                                           const float* __restrict__ v_w,
                                           const float* __restrict__ A,
                                           const float* __restrict__ normK,
                                           const float* __restrict__ normQ,
                                           float* __restrict__ wEff) {
    const int a = blockIdx.x, b = blockIdx.y;
    const int t = threadIdx.x;
    __shared__ float AS[4][16][128];
    __shared__ float kv[4][32][132];
    __shared__ float sc[2048];
    __shared__ float red[256];
    __shared__ float rowred[256];
    __shared__ float rowmax[16], rowsum[16];
    __shared__ float s_mu, s_rs;

    for (int idx = t; idx < 8192; idx += 256) {
        const int sk = idx >> 11, rr = (idx >> 7) & 15, cp = idx & 127;
        const int jq = (rr & 3) * 16 + 4 * a + (rr >> 2);
        AS[sk][rr][cp] = A[((size_t)(b * 4 + sk) * 64 + jq) * 128 + cp];
    }
    for (int idx = t; idx < 16384; idx += 256) {
        const int sk = idx >> 12, ckl = (idx >> 7) & 31, cp = idx & 127;
        kv[sk][ckl][cp] = k_w[((size_t)sk * 128 + 32 * a + ckl) * 128 + cp];
    }
    __syncthreads();
    for (int e = t; e < 2048; e += 256) {
        const int r = e >> 7, dd = e & 127;
        const int sk = dd & 3, ckl = dd >> 2;
        const float4* Ar = (const float4*)(&AS[sk][r][0]);
        const float4* kr = (const float4*)(&kv[sk][ckl][0]);
        float4 pv = {0.f, 0.f, 0.f, 0.f};
#pragma unroll 8
        for (int jj = 0; jj < 32; ++jj) {
            const float4 h = Ar[jj], k4 = kr[jj];
            pv.x = fmaf(h.x, k4.x, pv.x);
            pv.y = fmaf(h.y, k4.y, pv.y);
            pv.z = fmaf(h.z, k4.z, pv.z);
            pv.w = fmaf(h.w, k4.w, pv.w);
        }
        const float dot = pv.x + pv.y + pv.z + pv.w;
        const int jq = (r & 3) * 16 + 4 * a + (r >> 2);
        const float qn = fmaxf(sqrtf(fmaxf(normQ[b * 64 + jq], 0.f)), 1e-12f);
        const float kn = fmaxf(sqrtf(fmaxf(normK[(size_t)(b * 4 + sk) * 128 + 32 * a + ckl], 0.f)), 1e-12f);
        sc[e] = dot / (qn * kn * 256.0f);
    }
    __syncthreads();
    // reload kv with v_w (all score reads of kv done; barriers below fence it)
    for (int idx = t; idx < 16384; idx += 256) {
        const int sk = idx >> 12, m = (idx >> 7) & 31, cp = idx & 127;
        kv[sk][m][cp] = v_w[((size_t)sk * 128 + 32 * a + m) * 128 + cp];
    }
    // mean
    {
        float p = 0.f;
        for (int e = t; e < 2048; e += 256) p += sc[e];
        red[t] = p; __syncthreads();
        for (int off = 128; off > 0; off >>= 1) {
            if (t < off) red[t] += red[t + off];
            __syncthreads();
        }
        if (t == 0) s_mu = red[0] * (1.f / 2048.f);
        __syncthreads();
    }
    // var
    {
        const float mu = s_mu;
        float p = 0.f;
        for (int e = t; e < 2048; e += 256) { const float z = sc[e] - mu; p += z * z; }
        red[t] = p; __syncthreads();
        for (int off = 128; off > 0; off >>= 1) {
            if (t < off) red[t] += red[t + off];
            __syncthreads();
        }
        if (t == 0) s_rs = rsqrtf(red[0] * (1.f / 2048.f) + 1e-5f);
        __syncthreads();
    }
    const float mu = s_mu, rs = s_rs;
    const int r = t >> 4, l = t & 15;
    // row max
    {
        float m = -1e30f;
#pragma unroll
        for (int j = 0; j < 8; ++j) {
            const float z = (sc[r * 128 + l + j * 16] - mu) * rs;
            m = fmaxf(m, z);
        }
        rowred[t] = m; __syncthreads();
        if (l == 0) {
            float m2 = rowred[r * 16];
            for (int j = 1; j < 16; ++j) m2 = fmaxf(m2, rowred[r * 16 + j]);
            rowmax[r] = m2;
        }
        __syncthreads();
    }
    // row sum of exp
    {
        float p = 0.f;
#pragma unroll
        for (int j = 0; j < 8; ++j) {
            const float z = (sc[r * 128 + l + j * 16] - mu) * rs;
            p += expf(z - rowmax[r]);
        }
        rowred[t] = p; __syncthreads();
        if (l == 0) {
            float p2 = 0.f;
            for (int j = 0; j < 16; ++j) p2 += rowred[r * 16 + j];
            rowsum[r] = p2;
        }
        __syncthreads();
    }
    // attn back into sc
    {
        float vals[8];
#pragma unroll
        for (int j = 0; j < 8; ++j) {
            const float z = (sc[r * 128 + l + j * 16] - mu) * rs;
            vals[j] = expf(z - rowmax[r]) / rowsum[r];
        }
        __syncthreads();
#pragma unroll
        for (int j = 0; j < 8; ++j) sc[r * 128 + l + j * 16] = vals[j];
        __syncthreads();
    }
    // wEff from LDS v
    for (int e = t; e < 8192; e += 256) {
        const int sk = e >> 11, r2 = (e >> 7) & 15, cp = e & 127;
        float w = 0.f;
#pragma unroll
        for (int m = 0; m < 32; ++m)
            w = fmaf(sc[r2 * 128 + 4 * m + sk], kv[sk][m][cp], w);
        wEff[((size_t)(b * 4 + sk) * 64 + (a * 16 + r2)) * 128 + cp] = w;
    }
}

// ---------------------------------------------------------------------------
// K2c: wFinal_s[o][c'] = bnscale_o * sum_j out_w[o][j]*wEff_s[j][c']
// grid (s=4, b=4), 256 threads, wEff staged in LDS.
// ---------------------------------------------------------------------------
__global__ __launch_bounds__(256) void k2c(const float* __restrict__ out_w,
                                           const float* __restrict__ bn_gamma,
                                           const float* __restrict__ bn_var,
                                           const float* __restrict__ wEff,
                                           float* __restrict__ wFinal) {
    const int s = blockIdx.x, b = blockIdx.y;
    const int t = threadIdx.x;
    __shared__ float we[64][128];
    for (int idx = t; idx < 8192; idx += 256) {
        const int j = idx >> 7, cp = idx & 127;
        we[j][cp] = wEff[((size_t)(b * 4 + s) * 64 + j) * 128 + cp];
    }
    __syncthreads();
    for (int e = t; e < 2048; e += 256) {
        const int o = e >> 7, cp = e & 127;
        float w = 0.f;
#pragma unroll 16
        for (int j = 0; j < 64; ++j)
            w = fmaf(out_w[o * 64 + j], we[j][cp], w);
        const float scale = bn_gamma[o] * rsqrtf(bn_var[o] + 1e-5f);
        wFinal[((size_t)(b * 4 + s) * 16 + o) * 128 + cp] = w * scale;
    }
}

// ---------------------------------------------------------------------------
// K3: out[o,pix] = relu( sum_s wFinal_s[o]·sur_s(pix) + bias_o )
// grid (128 row-pairs, b=4), 256 threads; each thread 2 pixels
// ---------------------------------------------------------------------------
__global__ __launch_bounds__(256) void k3_out(const float* __restrict__ cen,
                                              const float* __restrict__ wFinal,
                                              const float* __restrict__ bn_gamma,
                                              const float* __restrict__ bn_beta,
                                              const float* __restrict__ bn_mean,
                                              const float* __restrict__ bn_var,
                                              float* __restrict__ out) {
    const int by = blockIdx.x;
    const int b  = blockIdx.y;
    const int t  = threadIdx.x;
    __shared__ __align__(16) float wf[NS * CSUR * 16];  // [s][c'][o]
    __shared__ __align__(16) float wc[16 * 16];         // [cin][o]

    for (int e = t; e < NS * CSUR * 16; e += 256) {
        const int s = e >> 11, cp = (e >> 4) & 127, o = e & 15;
        wf[e] = wFinal[((size_t)(b * NS + s) * 16 + o) * CSUR + cp];
    }
    __syncthreads();
    {
        const int cin = t >> 4, o = t & 15;
        float sum = 0.f;
#pragma unroll
        for (int s = 0; s < NS; ++s)
#pragma unroll
            for (int k = 0; k < 8; ++k)
                sum += wf[(s * CSUR + k * 16 + cin) * 16 + o];
        wc[cin * 16 + o] = sum;
    }
    __syncthreads();

    const int x0 = t & 127;
    const int x1 = x0 + 128;
    const int y  = by * 2 + (t >> 7);
    const float* cb = cen + (size_t)b * CIN * AREA;

    float acc0[16], acc1[16];
#pragma unroll
    for (int o = 0; o < 16; ++o) { acc0[o] = 0.f; acc1[o] = 0.f; }

    for (int s = 0; s < NS; ++s) {
        const int d = 1 << s;
        for (int k = 0; k < 8; ++k) {
            const int ry  = refl(y + c_dy[k] * d);
            const int rx0 = refl(x0 + c_dx[k] * d);
            const int rx1 = refl(x1 + c_dx[k] * d);
            const float* crow = cb + ry * WW;
#pragma unroll
            for (int cin = 0; cin < 16; ++cin) {
                const float v0 = crow[cin * AREA + rx0];
                const float v1 = crow[cin * AREA + rx1];
                const float4* w4 = reinterpret_cast<const float4*>(&wf[(s * CSUR + k * 16 + cin) * 16]);
#pragma unroll
                for (int oq = 0; oq < 4; ++oq) {
                    const float4 w = w4[oq];
                    acc0[oq*4+0] = fmaf(w.x, v0, acc0[oq*4+0]); acc1[oq*4+0] = fmaf(w.x, v1, acc1[oq*4+0]);
                    acc0[oq*4+1] = fmaf(w.y, v0, acc0[oq*4+1]); acc1[oq*4+1] = fmaf(w.y, v1, acc1[oq*4+1]);
                    acc0[oq*4+2] = fmaf(w.z, v0, acc0[oq*4+2]); acc1[oq*4+2] = fmaf(w.z, v1, acc1[oq*4+2]);
                    acc0[oq*4+3] = fmaf(w.w, v0, acc0[oq*4+3]); acc1[oq*4+3] = fmaf(w.w, v1, acc1[oq*4+3]);
                }
            }
        }
    }
    // center subtraction
    {
        const float* crow = cb + y * WW;
#pragma unroll
        for (int cin = 0; cin < 16; ++cin) {
            const float v0 = crow[cin * AREA + x0];
            const float v1 = crow[cin * AREA + x1];
            const float4* w4 = reinterpret_cast<const float4*>(&wc[cin * 16]);
#pragma unroll
            for (int oq = 0; oq < 4; ++oq) {
                const float4 w = w4[oq];
                acc0[oq*4+0] = fmaf(-w.x, v0, acc0[oq*4+0]); acc1[oq*4+0] = fmaf(-w.x, v1, acc1[oq*4+0]);
                acc0[oq*4+1] = fmaf(-w.y, v0, acc0[oq*4+1]); acc1[oq*4+1] = fmaf(-w.y, v1, acc1[oq*4+1]);
                acc0[oq*4+2] = fmaf(-w.z, v0, acc0[oq*4+2]); acc1[oq*4+2] = fmaf(-w.z, v1, acc1[oq*4+2]);
                acc0[oq*4+3] = fmaf(-w.w, v0, acc0[oq*4+3]); acc1[oq*4+3] = fmaf(-w.w, v1, acc1[oq*4+3]);
            }
        }
    }
#pragma unroll
    for (int o = 0; o < 16; ++o) {
        const float scale = bn_gamma[o] * rsqrtf(bn_var[o] + 1e-5f);
        const float bias  = bn_beta[o] - bn_mean[o] * scale;
        const float r0 = fmaxf(acc0[o] + bias, 0.f);
        const float r1 = fmaxf(acc1[o] + bias, 0.f);
        out[((size_t)(b * 16 + o) * HH + y) * WW + x0] = r0;
        out[((size_t)(b * 16 + o) * HH + y) * WW + x1] = r1;
    }
}

// ---------------------------------------------------------------------------
extern "C" void kernel_launch(void* const* d_in, const int* in_sizes, int n_in,
                              void* d_out, int out_size, void* d_ws, size_t ws_size,
                              hipStream_t stream) {
    const float* cen      = (const float*)d_in[0];
    const float* q_w      = (const float*)d_in[1];
    const float* k_w      = (const float*)d_in[2];
    const float* v_w      = (const float*)d_in[3];
    const float* out_w    = (const float*)d_in[4];
    const float* bn_gamma = (const float*)d_in[5];
    const float* bn_beta  = (const float*)d_in[6];
    const float* bn_mean  = (const float*)d_in[7];
    const float* bn_var   = (const float*)d_in[8];
    float* out = (float*)d_out;

    char* ws = (char*)d_ws;
    const size_t TPART_BYTES = (size_t)4 * 16 * 20736 * 4;   // 5,308,416
    const size_t GFULL_BYTES = (size_t)16 * 20736 * 4;       // 1,327,104
    const size_t A_BYTES     = (size_t)16 * 64 * 128 * 4;    //   524,288
    const size_t NK_BYTES    = (size_t)16 * 128 * 4;         //     8,192
    const size_t NQ_BYTES    = (size_t)4 * 64 * 4;           //     1,024
    const size_t WEFF_BYTES  = (size_t)16 * 64 * 128 * 4;    //   524,288

    float* Tpart = (float*)(ws);
    float* Gfull = (float*)(ws + TPART_BYTES);
    float* A     = (float*)(ws + TPART_BYTES + GFULL_BYTES);
    float* normK = (float*)(ws + TPART_BYTES + GFULL_BYTES + A_BYTES);
    float* normQ = (float*)(ws + TPART_BYTES + GFULL_BYTES + A_BYTES + NK_BYTES);
    float* wEff  = (float*)(ws + TPART_BYTES + GFULL_BYTES + A_BYTES + NK_BYTES + NQ_BYTES);
    float* wFin  = (float*)(ws + TPART_BYTES + GFULL_BYTES + A_BYTES + NK_BYTES + NQ_BYTES + WEFF_BYTES);

    (void)hipMemsetAsync(Tpart, 0, TPART_BYTES, stream);
    k1_gram_mfma<<<dim3(32, 4, 4), 256, 0, stream>>>(cen, Tpart);
    k1b<<<dim3(4, 4), 256, 0, stream>>>(Tpart, Gfull);
    k2a<<<dim3(4, 4, 4), 256, 0, stream>>>(q_w, k_w, Gfull, A, normK, normQ);
    k2b<<<dim3(4, 4), 256, 0, stream>>>(k_w, v_w, A, normK, normQ, wEff);
    k2c<<<dim3(4, 4), 256, 0, stream>>>(out_w, bn_gamma, bn_var, wEff, wFin);
    k3_out<<<dim3(128, 4), 256, 0, stream>>>(cen, wFin, bn_gamma, bn_beta,
                                             bn_mean, bn_var, out);
}